// Round 4
// baseline (511.354 us; speedup 1.0000x reference)
//
#include <hip/hip_runtime.h>
#include <hip/hip_bf16.h>
#include <cstdint>
#include <cstddef>

namespace {

constexpr int kB = 512, kT = 32, kH = 768, kF = 3072, kE = 3;
constexpr int kMaxTiles = 131;  // sum ceil(cnt_e/4) <= 130
constexpr int kMaxChunk = 66;

typedef __attribute__((ext_vector_type(8))) short short8;
typedef __attribute__((ext_vector_type(4))) float f32x4;

__device__ __forceinline__ float bf2f(__hip_bfloat16 v) { return __bfloat162float(v); }
__device__ __forceinline__ short f2bfb(float f) {
  __hip_bfloat16 h = __float2bfloat16(f);
  return *reinterpret_cast<short*>(&h);
}

// ---- per-tensor dtype sniff: f32 data viewed as 16-bit words has ~25% of low
// words with bf16-exponent-field >= 0xC0; genuine bf16 (|v|<1e6) has none.
// nwords must be <= element count (so we never read past a bf16-sized buffer).
__global__ void k_sniff(const unsigned short* __restrict__ w, int nwords,
                        int* __restrict__ flag) {
  __shared__ int cnt_s;
  if (threadIdx.x == 0) cnt_s = 0;
  __syncthreads();
  int local = 0;
  for (int i = threadIdx.x; i < nwords; i += 256) {
    unsigned e = (w[i] >> 7) & 0xFF;
    if (e >= 0xC0) ++local;
  }
  atomicAdd(&cnt_s, local);
  __syncthreads();
  if (threadIdx.x == 0) *flag = (cnt_s > 64) ? 1 : 0;
}

// ---------------- routing: scores = softmax(mean_t(x) @ Wg^T), top-1 ----------------
__global__ void k_route(const void* __restrict__ xv, const void* __restrict__ Wgv,
                        const int* __restrict__ flagX, const int* __restrict__ flagG,
                        float* __restrict__ wsel,
                        int* __restrict__ cnt, int* __restrict__ lists) {
  bool fx = (*flagX != 0), fg = (*flagG != 0);
  const float* xf = (const float*)xv;
  const __hip_bfloat16* xb = (const __hip_bfloat16*)xv;
  const float* wf = (const float*)Wgv;
  const __hip_bfloat16* wb = (const __hip_bfloat16*)Wgv;
  int b = blockIdx.x;
  int tid = threadIdx.x;
  float a0 = 0.f, a1 = 0.f, a2 = 0.f;
  for (int h = tid; h < kH; h += 256) {
    size_t base = (size_t)b * kT * kH + h;
    float s = 0.f;
#pragma unroll
    for (int t = 0; t < kT; ++t) {
      size_t i = base + (size_t)t * kH;
      s += fx ? xf[i] : bf2f(xb[i]);
    }
    s *= (1.f / kT);
    a0 += s * (fg ? wf[0 * kH + h] : bf2f(wb[0 * kH + h]));
    a1 += s * (fg ? wf[1 * kH + h] : bf2f(wb[1 * kH + h]));
    a2 += s * (fg ? wf[2 * kH + h] : bf2f(wb[2 * kH + h]));
  }
  __shared__ float red[3][256];
  red[0][tid] = a0; red[1][tid] = a1; red[2][tid] = a2;
  __syncthreads();
  for (int s2 = 128; s2 > 0; s2 >>= 1) {
    if (tid < s2) {
      red[0][tid] += red[0][tid + s2];
      red[1][tid] += red[1][tid + s2];
      red[2][tid] += red[2][tid + s2];
    }
    __syncthreads();
  }
  if (tid == 0) {
    float l0 = red[0][0], l1 = red[1][0], l2 = red[2][0];
    int am = 0; float mx = l0;
    if (l1 > mx) { mx = l1; am = 1; }
    if (l2 > mx) { mx = l2; am = 2; }
    float e0 = expf(l0 - mx), e1 = expf(l1 - mx), e2 = expf(l2 - mx);
    float inv = 1.f / (e0 + e1 + e2);
    float sc = (am == 0 ? e0 : (am == 1 ? e1 : e2)) * inv;
    wsel[b] = sc;
    int pos = atomicAdd(&cnt[am], 1);
    lists[am * kB + pos] = b;
  }
}

// ---------------- pack same-expert batches into 4-batch (128-row) M-tiles ----------------
__global__ void k_tiles(const int* __restrict__ cnt, const int* __restrict__ lists,
                        int* __restrict__ tileExpert, int* __restrict__ tileBatch,
                        int* __restrict__ numTiles) {
  if (threadIdx.x == 0 && blockIdx.x == 0) {
    int t = 0;
    for (int e = 0; e < kE; ++e) {
      int c = cnt[e];
      for (int i = 0; i < c; i += 4) {
        tileExpert[t] = e;
        for (int s = 0; s < 4; ++s)
          tileBatch[t * 4 + s] = (i + s < c) ? lists[e * kB + i + s] : -1;
        ++t;
      }
    }
    *numTiles = t;
    for (int tt = t; tt < kMaxTiles; ++tt) {
      tileExpert[tt] = 0;
      for (int s = 0; s < 4; ++s) tileBatch[tt * 4 + s] = -1;
    }
  }
}

// ---------------- transpose + convert: src [E][K][N] (f32 or bf16 per flag) -> bf16 [E][N][K] ----------------
__global__ void k_transpose(const void* __restrict__ srcv, __hip_bfloat16* __restrict__ dst_,
                            int K, int N, const int* __restrict__ flag) {
  bool f32 = (*flag != 0);
  const float* sf = (const float*)srcv;
  const __hip_bfloat16* sb = (const __hip_bfloat16*)srcv;
  unsigned short* dst = (unsigned short*)dst_;
  __shared__ __align__(16) unsigned short t[64][65];
  int e = blockIdx.z;
  int n0 = blockIdx.x * 64, k0 = blockIdx.y * 64;
  size_t eoff = (size_t)e * K * N;
  unsigned short* d = dst + eoff;
  int c = threadIdx.x & 63, r4 = threadIdx.x >> 6;
#pragma unroll
  for (int r = r4; r < 64; r += 4) {
    size_t i = eoff + (size_t)(k0 + r) * N + n0 + c;
    float v = f32 ? sf[i] : bf2f(sb[i]);
    t[r][c] = (unsigned short)f2bfb(v);
  }
  __syncthreads();
#pragma unroll
  for (int r = r4; r < 64; r += 4)
    d[(size_t)(n0 + r) * K + k0 + c] = t[c][r];
}

// ---------------- GEMM1: h = gelu(x @ W1[e] + b1[e]) ----------------
// LDS layout (fragment order): elem(kk,m,q,j) at lds[(kk*128+m)*32 + q*8 + j]
__global__ __launch_bounds__(256, 2)
void k_ffn1(const void* __restrict__ xv,
            const __hip_bfloat16* __restrict__ w1t,  // [E][F][H] bf16 (n-major)
            const __hip_bfloat16* __restrict__ b1,   // [E][F] read as bf16 (zeros)
            const int* __restrict__ flagX,
            const int* __restrict__ tileExpert,
            const int* __restrict__ tileBatch,
            const int* __restrict__ numTiles,
            int tileOff,
            __hip_bfloat16* __restrict__ hbuf) {     // [chunk][128][F]
  int local = blockIdx.y;
  int tile = local + tileOff;
  if (tile >= *numTiles) return;
  bool fx = (*flagX != 0);
  const float* xf = (const float*)xv;
  const __hip_bfloat16* xb = (const __hip_bfloat16*)xv;
  int nbase = blockIdx.x * 128;
  int e = tileExpert[tile];
  int tb0 = tileBatch[tile * 4];
  int tb[4];
#pragma unroll
  for (int s = 0; s < 4; ++s) {
    int bb = tileBatch[tile * 4 + s];
    tb[s] = (bb < 0) ? tb0 : bb;
  }
  __shared__ __align__(16) short ldsA[128 * 64];
  __shared__ __align__(16) short ldsB[128 * 64];
  int tid = threadIdx.x;
  int lane = tid & 63, wid = tid >> 6;
  int wm = wid >> 1, wn = wid & 1;
  int lane16 = lane & 15, q8 = (lane >> 4) * 8;

  f32x4 acc[4][4];
#pragma unroll
  for (int r = 0; r < 4; ++r)
#pragma unroll
    for (int c = 0; c < 4; ++c) acc[r][c] = (f32x4)0.f;

  const __hip_bfloat16* w1e = w1t + (size_t)e * kF * kH;
  size_t offA[4];
  const __hip_bfloat16* gB[4];
  short* lA[4];
  short* lB[4];
#pragma unroll
  for (int it = 0; it < 4; ++it) {
    int c = it * 256 + tid;
    int q = c & 3, m = (c >> 2) & 127, kk = c >> 9;
    int row = tb[m >> 5] * kT + (m & 31);
    offA[it] = (size_t)row * kH + kk * 32 + q * 8;
    gB[it] = w1e + (size_t)(nbase + m) * kH + kk * 32 + q * 8;
    lA[it] = &ldsA[c * 8];
    lB[it] = &ldsB[c * 8];
  }

  for (int k0 = 0; k0 < kH; k0 += 64) {
    short8 va[4], vb[4];
    if (fx) {
#pragma unroll
      for (int it = 0; it < 4; ++it) {
        const float* p = xf + offA[it] + k0;
        float4 u = *(const float4*)p;
        float4 w = *(const float4*)(p + 4);
        short8 v;
        v[0] = f2bfb(u.x); v[1] = f2bfb(u.y); v[2] = f2bfb(u.z); v[3] = f2bfb(u.w);
        v[4] = f2bfb(w.x); v[5] = f2bfb(w.y); v[6] = f2bfb(w.z); v[7] = f2bfb(w.w);
        va[it] = v;
      }
    } else {
#pragma unroll
      for (int it = 0; it < 4; ++it) va[it] = *(const short8*)(xb + offA[it] + k0);
    }
#pragma unroll
    for (int it = 0; it < 4; ++it) vb[it] = *(const short8*)(gB[it] + k0);
    __syncthreads();  // previous iter's ds_reads complete before overwrite
#pragma unroll
    for (int it = 0; it < 4; ++it) *(short8*)lA[it] = va[it];
#pragma unroll
    for (int it = 0; it < 4; ++it) *(short8*)lB[it] = vb[it];
    __syncthreads();
#pragma unroll
    for (int kk = 0; kk < 2; ++kk) {
      short8 af[4], bfr[4];
#pragma unroll
      for (int r = 0; r < 4; ++r)
        af[r] = *(const short8*)&ldsA[(kk * 128 + wm * 64 + r * 16 + lane16) * 32 + q8];
#pragma unroll
      for (int c = 0; c < 4; ++c)
        bfr[c] = *(const short8*)&ldsB[(kk * 128 + wn * 64 + c * 16 + lane16) * 32 + q8];
#pragma unroll
      for (int r = 0; r < 4; ++r)
#pragma unroll
        for (int c = 0; c < 4; ++c)
          acc[r][c] = __builtin_amdgcn_mfma_f32_16x16x32_bf16(af[r], bfr[c], acc[r][c], 0, 0, 0);
    }
  }

  int q4 = (lane >> 4) * 4;
#pragma unroll
  for (int c = 0; c < 4; ++c) {
    int ncol = wn * 64 + c * 16 + lane16;
    float bias = bf2f(b1[e * kF + nbase + ncol]);
#pragma unroll
    for (int r = 0; r < 4; ++r) {
#pragma unroll
      for (int g = 0; g < 4; ++g) {
        int m = wm * 64 + r * 16 + q4 + g;
        float v = acc[r][c][g] + bias;
        float ge = 0.5f * v * (1.f + erff(v * 0.70710678118654752f));
        hbuf[((size_t)(local * 128 + m)) * kF + nbase + ncol] = __float2bfloat16(ge);
      }
    }
  }
}

// ---------------- GEMM2: out = (h @ W2[e] + b2[e]) * score, scatter; out is FLOAT32 ----------------
__global__ __launch_bounds__(256, 2)
void k_ffn2(const __hip_bfloat16* __restrict__ hbuf,
            const __hip_bfloat16* __restrict__ w2t,  // [E][H][F] bf16 (n-major)
            const __hip_bfloat16* __restrict__ b2,   // [E][H] read as bf16 (zeros)
            const float* __restrict__ wsel,
            const int* __restrict__ tileExpert,
            const int* __restrict__ tileBatch,
            const int* __restrict__ numTiles,
            int tileOff,
            float* __restrict__ out) {
  int local = blockIdx.y;
  int tile = local + tileOff;
  if (tile >= *numTiles) return;
  int nbase = blockIdx.x * 128;
  int e = tileExpert[tile];
  int tbraw[4];
  float sc[4];
#pragma unroll
  for (int s = 0; s < 4; ++s) {
    int bb = tileBatch[tile * 4 + s];
    tbraw[s] = bb;
    sc[s] = (bb >= 0) ? wsel[bb] : 0.f;
  }
  __shared__ __align__(16) short ldsA[128 * 64];
  __shared__ __align__(16) short ldsB[128 * 64];
  int tid = threadIdx.x;
  int lane = tid & 63, wid = tid >> 6;
  int wm = wid >> 1, wn = wid & 1;
  int lane16 = lane & 15, q8 = (lane >> 4) * 8;

  f32x4 acc[4][4];
#pragma unroll
  for (int r = 0; r < 4; ++r)
#pragma unroll
    for (int c = 0; c < 4; ++c) acc[r][c] = (f32x4)0.f;

  const __hip_bfloat16* w2e = w2t + (size_t)e * kF * kH;
  const __hip_bfloat16* arow = hbuf + (size_t)local * 128 * kF;
  const __hip_bfloat16* gA[4];
  const __hip_bfloat16* gB[4];
  short* lA[4];
  short* lB[4];
#pragma unroll
  for (int it = 0; it < 4; ++it) {
    int c = it * 256 + tid;
    int q = c & 3, m = (c >> 2) & 127, kk = c >> 9;
    gA[it] = arow + (size_t)m * kF + kk * 32 + q * 8;
    gB[it] = w2e + (size_t)(nbase + m) * kF + kk * 32 + q * 8;
    lA[it] = &ldsA[c * 8];
    lB[it] = &ldsB[c * 8];
  }

  for (int k0 = 0; k0 < kF; k0 += 64) {
    short8 va[4], vb[4];
#pragma unroll
    for (int it = 0; it < 4; ++it) va[it] = *(const short8*)(gA[it] + k0);
#pragma unroll
    for (int it = 0; it < 4; ++it) vb[it] = *(const short8*)(gB[it] + k0);
    __syncthreads();
#pragma unroll
    for (int it = 0; it < 4; ++it) *(short8*)lA[it] = va[it];
#pragma unroll
    for (int it = 0; it < 4; ++it) *(short8*)lB[it] = vb[it];
    __syncthreads();
#pragma unroll
    for (int kk = 0; kk < 2; ++kk) {
      short8 af[4], bfr[4];
#pragma unroll
      for (int r = 0; r < 4; ++r)
        af[r] = *(const short8*)&ldsA[(kk * 128 + wm * 64 + r * 16 + lane16) * 32 + q8];
#pragma unroll
      for (int c = 0; c < 4; ++c)
        bfr[c] = *(const short8*)&ldsB[(kk * 128 + wn * 64 + c * 16 + lane16) * 32 + q8];
#pragma unroll
      for (int r = 0; r < 4; ++r)
#pragma unroll
        for (int c = 0; c < 4; ++c)
          acc[r][c] = __builtin_amdgcn_mfma_f32_16x16x32_bf16(af[r], bfr[c], acc[r][c], 0, 0, 0);
    }
  }

  int q4 = (lane >> 4) * 4;
#pragma unroll
  for (int c = 0; c < 4; ++c) {
    int ncol = wn * 64 + c * 16 + lane16;
    float bias = bf2f(b2[e * kH + nbase + ncol]);
#pragma unroll
    for (int r = 0; r < 4; ++r) {
      int s = (wm * 64 + r * 16) >> 5;
      int bb = tbraw[s];
      if (bb < 0) continue;
      float scale = sc[s];
#pragma unroll
      for (int g = 0; g < 4; ++g) {
        int m = wm * 64 + r * 16 + q4 + g;
        float v = (acc[r][c][g] + bias) * scale;
        out[((size_t)(bb * kT + (m & 31))) * kH + nbase + ncol] = v;
      }
    }
  }
}

}  // namespace

extern "C" void kernel_launch(void* const* d_in, const int* in_sizes, int n_in,
                              void* d_out, int out_size, void* d_ws, size_t ws_size,
                              hipStream_t stream) {
  (void)in_sizes; (void)n_in; (void)out_size;
  float* out = (float*)d_out;

  char* ws = (char*)d_ws;
  size_t off = 0;
  auto alloc = [&](size_t bytes) -> char* {
    char* p = ws + off;
    off = (off + bytes + 255) & ~(size_t)255;
    return p;
  };
  int*   flagX      = (int*)alloc(4);
  int*   flagG      = (int*)alloc(4);
  int*   flagW1     = (int*)alloc(4);
  int*   flagW2     = (int*)alloc(4);
  int*   cnt        = (int*)alloc(kE * 4);
  float* wsel       = (float*)alloc(kB * 4);
  int*   lists      = (int*)alloc((size_t)kE * kB * 4);
  int*   tileExpert = (int*)alloc(kMaxTiles * 4);
  int*   tileBatch  = (int*)alloc(kMaxTiles * 4 * 4);
  int*   numTiles   = (int*)alloc(4);
  __hip_bfloat16* w1t = (__hip_bfloat16*)alloc((size_t)kE * kH * kF * 2);  // 14.2 MB
  __hip_bfloat16* w2t = (__hip_bfloat16*)alloc((size_t)kE * kH * kF * 2);  // 14.2 MB

  // adaptive hbuf chunk: fit in remaining workspace (deterministic in ws_size)
  size_t tileBytes = (size_t)128 * kF * 2;  // 786432
  size_t avail = (ws_size > off + tileBytes) ? (ws_size - off) : tileBytes;
  int chunk = (int)(avail / tileBytes);
  if (chunk > kMaxChunk) chunk = kMaxChunk;
  if (chunk < 1) chunk = 1;
  __hip_bfloat16* hbuf = (__hip_bfloat16*)alloc((size_t)chunk * tileBytes);

  hipMemsetAsync(cnt, 0, kE * 4, stream);
  // per-tensor dtype sniff; nwords <= element count so bf16-sized buffers aren't overrun
  k_sniff<<<1, 256, 0, stream>>>((const unsigned short*)d_in[0], 4096, flagX);
  k_sniff<<<1, 256, 0, stream>>>((const unsigned short*)d_in[1], kE * kH, flagG);
  k_sniff<<<1, 256, 0, stream>>>((const unsigned short*)d_in[2], 4096, flagW1);
  k_sniff<<<1, 256, 0, stream>>>((const unsigned short*)d_in[4], 4096, flagW2);
  k_route<<<kB, 256, 0, stream>>>(d_in[0], d_in[1], flagX, flagG, wsel, cnt, lists);
  k_tiles<<<1, 64, 0, stream>>>(cnt, lists, tileExpert, tileBatch, numTiles);
  k_transpose<<<dim3(kF / 64, kH / 64, kE), 256, 0, stream>>>(d_in[2], w1t, kH, kF, flagW1);
  k_transpose<<<dim3(kH / 64, kF / 64, kE), 256, 0, stream>>>(d_in[4], w2t, kF, kH, flagW2);
  for (int toff = 0; toff < kMaxTiles; toff += chunk) {
    k_ffn1<<<dim3(kF / 128, chunk), 256, 0, stream>>>(d_in[0], w1t,
                                                      (const __hip_bfloat16*)d_in[3], flagX,
                                                      tileExpert, tileBatch, numTiles,
                                                      toff, hbuf);
    k_ffn2<<<dim3(kH / 128, chunk), 256, 0, stream>>>(hbuf, w2t,
                                                      (const __hip_bfloat16*)d_in[5], wsel,
                                                      tileExpert, tileBatch, numTiles,
                                                      toff, out);
  }
}

// Round 5
// 458.781 us; speedup vs baseline: 1.1146x; 1.1146x over previous
//
#include <hip/hip_runtime.h>
#include <hip/hip_bf16.h>
#include <cstdint>
#include <cstddef>

namespace {

constexpr int kB = 512, kT = 32, kH = 768, kF = 3072, kE = 3;
constexpr int kMaxTiles = 131;   // sum ceil(cnt_e/4) <= 131
constexpr int kMaxChunk = 131;
constexpr int kXPermTile = 128 * kH;   // 98304 elts per tile
constexpr int kHbufTile  = 128 * kF;   // 393216 elts per tile

typedef __attribute__((ext_vector_type(8))) short short8;
typedef __attribute__((ext_vector_type(4))) float f32x4;

__device__ __forceinline__ void gld_lds16(const void* g, void* l) {
  __builtin_amdgcn_global_load_lds(
      (const __attribute__((address_space(1))) void*)g,
      (__attribute__((address_space(3))) void*)l, 16, 0, 0);
}

__device__ __forceinline__ float bf2f(__hip_bfloat16 v) { return __bfloat162float(v); }
__device__ __forceinline__ short f2bfb(float f) {
  __hip_bfloat16 h = __float2bfloat16(f);
  return *reinterpret_cast<short*>(&h);
}

// ---- per-tensor dtype sniff (f32 seen as 16-bit words: ~25% have exp-field >= 0xC0)
__global__ void k_sniff(const unsigned short* __restrict__ w, int nwords,
                        int* __restrict__ flag) {
  __shared__ int cnt_s;
  if (threadIdx.x == 0) cnt_s = 0;
  __syncthreads();
  int local = 0;
  for (int i = threadIdx.x; i < nwords; i += 256) {
    unsigned e = (w[i] >> 7) & 0xFF;
    if (e >= 0xC0) ++local;
  }
  atomicAdd(&cnt_s, local);
  __syncthreads();
  if (threadIdx.x == 0) *flag = (cnt_s > 64) ? 1 : 0;
}

// ---------------- routing ----------------
__global__ void k_route(const void* __restrict__ xv, const void* __restrict__ Wgv,
                        const int* __restrict__ flagX, const int* __restrict__ flagG,
                        float* __restrict__ wsel,
                        int* __restrict__ cnt, int* __restrict__ lists) {
  bool fx = (*flagX != 0), fg = (*flagG != 0);
  const float* xf = (const float*)xv;
  const __hip_bfloat16* xb = (const __hip_bfloat16*)xv;
  const float* wf = (const float*)Wgv;
  const __hip_bfloat16* wb = (const __hip_bfloat16*)Wgv;
  int b = blockIdx.x;
  int tid = threadIdx.x;
  float a0 = 0.f, a1 = 0.f, a2 = 0.f;
  for (int h = tid; h < kH; h += 256) {
    size_t base = (size_t)b * kT * kH + h;
    float s = 0.f;
#pragma unroll
    for (int t = 0; t < kT; ++t) {
      size_t i = base + (size_t)t * kH;
      s += fx ? xf[i] : bf2f(xb[i]);
    }
    s *= (1.f / kT);
    a0 += s * (fg ? wf[0 * kH + h] : bf2f(wb[0 * kH + h]));
    a1 += s * (fg ? wf[1 * kH + h] : bf2f(wb[1 * kH + h]));
    a2 += s * (fg ? wf[2 * kH + h] : bf2f(wb[2 * kH + h]));
  }
  __shared__ float red[3][256];
  red[0][tid] = a0; red[1][tid] = a1; red[2][tid] = a2;
  __syncthreads();
  for (int s2 = 128; s2 > 0; s2 >>= 1) {
    if (tid < s2) {
      red[0][tid] += red[0][tid + s2];
      red[1][tid] += red[1][tid + s2];
      red[2][tid] += red[2][tid + s2];
    }
    __syncthreads();
  }
  if (tid == 0) {
    float l0 = red[0][0], l1 = red[1][0], l2 = red[2][0];
    int am = 0; float mx = l0;
    if (l1 > mx) { mx = l1; am = 1; }
    if (l2 > mx) { mx = l2; am = 2; }
    float e0 = expf(l0 - mx), e1 = expf(l1 - mx), e2 = expf(l2 - mx);
    float inv = 1.f / (e0 + e1 + e2);
    float sc = (am == 0 ? e0 : (am == 1 ? e1 : e2)) * inv;
    wsel[b] = sc;
    int pos = atomicAdd(&cnt[am], 1);
    lists[am * kB + pos] = b;
  }
}

// ---------------- pack batches into 128-row M-tiles ----------------
__global__ void k_tiles(const int* __restrict__ cnt, const int* __restrict__ lists,
                        int* __restrict__ tileExpert, int* __restrict__ tileBatch,
                        int* __restrict__ numTiles) {
  if (threadIdx.x == 0 && blockIdx.x == 0) {
    int t = 0;
    for (int e = 0; e < kE; ++e) {
      int c = cnt[e];
      for (int i = 0; i < c; i += 4) {
        tileExpert[t] = e;
        for (int s = 0; s < 4; ++s)
          tileBatch[t * 4 + s] = (i + s < c) ? lists[e * kB + i + s] : -1;
        ++t;
      }
    }
    *numTiles = t;
    for (int tt = t; tt < kMaxTiles; ++tt) {
      tileExpert[tt] = 0;
      for (int s = 0; s < 4; ++s) tileBatch[tt * 4 + s] = -1;
    }
  }
}

// ---------------- transpose + convert: src [E][K][N] -> bf16 [E][N][K] ----------------
__global__ void k_transpose(const void* __restrict__ srcv, __hip_bfloat16* __restrict__ dst_,
                            int K, int N, const int* __restrict__ flag) {
  bool f32 = (*flag != 0);
  const float* sf = (const float*)srcv;
  const __hip_bfloat16* sb = (const __hip_bfloat16*)srcv;
  unsigned short* dst = (unsigned short*)dst_;
  __shared__ __align__(16) unsigned short t[64][65];
  int e = blockIdx.z;
  int n0 = blockIdx.x * 64, k0 = blockIdx.y * 64;
  size_t eoff = (size_t)e * K * N;
  unsigned short* d = dst + eoff;
  int c = threadIdx.x & 63, r4 = threadIdx.x >> 6;
#pragma unroll
  for (int r = r4; r < 64; r += 4) {
    size_t i = eoff + (size_t)(k0 + r) * N + n0 + c;
    float v = f32 ? sf[i] : bf2f(sb[i]);
    t[r][c] = (unsigned short)f2bfb(v);
  }
  __syncthreads();
#pragma unroll
  for (int r = r4; r < 64; r += 4)
    d[(size_t)(n0 + r) * K + k0 + c] = t[c][r];
}

// ---------------- convert + permute x into ffn1 A-staging order ----------------
// xperm[tile][kblk(12)][slot(1024)*8], slot = kk*512 + m*4 + (q ^ ((m>>1)&3))
__global__ __launch_bounds__(256)
void k_convert_x(const void* __restrict__ xv, const int* __restrict__ flagX,
                 const int* __restrict__ tileBatch, const int* __restrict__ numTiles,
                 __hip_bfloat16* __restrict__ xperm) {
  int tile = blockIdx.y;
  if (tile >= *numTiles) return;
  int kblk = blockIdx.x;
  bool fx = (*flagX != 0);
  const float* xf = (const float*)xv;
  const __hip_bfloat16* xb = (const __hip_bfloat16*)xv;
  int tb0 = tileBatch[tile * 4];
  int tb[4];
#pragma unroll
  for (int s = 0; s < 4; ++s) {
    int bb = tileBatch[tile * 4 + s];
    tb[s] = (bb < 0) ? tb0 : bb;
  }
  int tid = threadIdx.x;
  short8* dst = (short8*)(xperm + (size_t)tile * kXPermTile + kblk * 8192);
#pragma unroll
  for (int i = 0; i < 4; ++i) {
    int s = i * 256 + tid;
    int m = (s >> 2) & 127, kk = s >> 9;
    int q = (s & 3) ^ ((s >> 3) & 3);   // (m>>1)&3 == (s>>3)&3
    int row = tb[m >> 5] * kT + (m & 31);
    size_t src = (size_t)row * kH + kblk * 64 + kk * 32 + q * 8;
    short8 v;
    if (fx) {
      float4 u = *(const float4*)(xf + src);
      float4 w = *(const float4*)(xf + src + 4);
      v[0] = f2bfb(u.x); v[1] = f2bfb(u.y); v[2] = f2bfb(u.z); v[3] = f2bfb(u.w);
      v[4] = f2bfb(w.x); v[5] = f2bfb(w.y); v[6] = f2bfb(w.z); v[7] = f2bfb(w.w);
    } else {
      v = *(const short8*)(xb + src);
    }
    dst[s] = v;
  }
}

// ---------------- GEMM1: h = gelu(x @ W1[e] + b1), hbuf in ffn2-A-staging order ----------------
__global__ __launch_bounds__(256, 2)
void k_ffn1(const __hip_bfloat16* __restrict__ xperm,
            const __hip_bfloat16* __restrict__ w1t,  // [E][F][H] bf16
            const __hip_bfloat16* __restrict__ b1,
            const int* __restrict__ tileExpert,
            const int* __restrict__ numTiles,
            int tileOff,
            __hip_bfloat16* __restrict__ hbuf) {
  int local = blockIdx.y;
  int tile = local + tileOff;
  if (tile >= *numTiles) return;
  int nbase = blockIdx.x * 128;
  int e = tileExpert[tile];
  __shared__ __align__(16) short ldsA[8192];
  __shared__ __align__(16) short ldsB[8192];
  int tid = threadIdx.x;
  int lane = tid & 63, wid = tid >> 6;
  int wm = wid >> 1, wn = wid & 1;
  int lane16 = lane & 15, qf = lane >> 4;
  int swzl = (lane16 >> 1) & 3;          // (m>>1)&3 for m = base16 + lane16
  int qx = (qf ^ swzl) * 8;              // swizzled element offset for ds_read

  f32x4 acc[4][4];
#pragma unroll
  for (int r = 0; r < 4; ++r)
#pragma unroll
    for (int c = 0; c < 4; ++c) acc[r][c] = (f32x4)0.f;

  const __hip_bfloat16* w1e = w1t + (size_t)e * kF * kH;
  const __hip_bfloat16* xtile = xperm + (size_t)tile * kXPermTile;
  const __hip_bfloat16* gB[4];
  short* lA[4];
  short* lB[4];
  int aoff[4];
#pragma unroll
  for (int it = 0; it < 4; ++it) {
    int s = it * 256 + tid;
    int m = (s >> 2) & 127, kk = s >> 9;
    int q = (s & 3) ^ ((s >> 3) & 3);
    aoff[it] = s * 8;
    gB[it] = w1e + (size_t)(nbase + m) * kH + kk * 32 + q * 8;
    lA[it] = &ldsA[s * 8];
    lB[it] = &ldsB[s * 8];
  }

  for (int k0 = 0; k0 < kH; k0 += 64) {
#pragma unroll
    for (int it = 0; it < 4; ++it) gld_lds16(xtile + k0 * 128 + aoff[it], lA[it]);
#pragma unroll
    for (int it = 0; it < 4; ++it) gld_lds16(gB[it] + k0, lB[it]);
    __syncthreads();
#pragma unroll
    for (int kk = 0; kk < 2; ++kk) {
      short8 af[4], bfr[4];
#pragma unroll
      for (int r = 0; r < 4; ++r) {
        int mr = wm * 64 + r * 16 + lane16;
        af[r] = *(const short8*)&ldsA[(kk * 512 + mr * 4) * 8 + qx];
      }
#pragma unroll
      for (int c = 0; c < 4; ++c) {
        int mb = wn * 64 + c * 16 + lane16;
        bfr[c] = *(const short8*)&ldsB[(kk * 512 + mb * 4) * 8 + qx];
      }
#pragma unroll
      for (int r = 0; r < 4; ++r)
#pragma unroll
        for (int c = 0; c < 4; ++c)
          acc[r][c] = __builtin_amdgcn_mfma_f32_16x16x32_bf16(af[r], bfr[c], acc[r][c], 0, 0, 0);
    }
    __syncthreads();
  }

  // epilogue: write gelu(acc+bias) into hbuf in ffn2 A-staging order
  __hip_bfloat16* htile = hbuf + (size_t)local * kHbufTile;
  int q4 = qf * 4;
#pragma unroll
  for (int c = 0; c < 4; ++c) {
    int n = nbase + wn * 64 + c * 16 + lane16;
    int kblk2 = n >> 6, kkn = (n >> 5) & 1, qn = (n >> 3) & 3, j = n & 7;
    float bias = bf2f(b1[e * kF + n]);
    __hip_bfloat16* hb = htile + kblk2 * 8192 + kkn * 4096 + j;
#pragma unroll
    for (int r = 0; r < 4; ++r) {
#pragma unroll
      for (int g = 0; g < 4; ++g) {
        int m = wm * 64 + r * 16 + q4 + g;
        float v = acc[r][c][g] + bias;
        float ge = 0.5f * v * (1.f + erff(v * 0.70710678118654752f));
        hb[(m * 4 + (qn ^ ((m >> 1) & 3))) * 8] = __float2bfloat16(ge);
      }
    }
  }
}

// ---------------- GEMM2: out = (h @ W2[e] + b2) * score, f32 scatter ----------------
__global__ __launch_bounds__(256, 2)
void k_ffn2(const __hip_bfloat16* __restrict__ hbuf,
            const __hip_bfloat16* __restrict__ w2t,  // [E][H][F] bf16
            const __hip_bfloat16* __restrict__ b2,
            const float* __restrict__ wsel,
            const int* __restrict__ tileExpert,
            const int* __restrict__ tileBatch,
            const int* __restrict__ numTiles,
            int tileOff,
            float* __restrict__ out) {
  int local = blockIdx.y;
  int tile = local + tileOff;
  if (tile >= *numTiles) return;
  int nbase = blockIdx.x * 128;
  int e = tileExpert[tile];
  int tbraw[4];
  float sc[4];
#pragma unroll
  for (int s = 0; s < 4; ++s) {
    int bb = tileBatch[tile * 4 + s];
    tbraw[s] = bb;
    sc[s] = (bb >= 0) ? wsel[bb] : 0.f;
  }
  __shared__ __align__(16) short ldsA[8192];
  __shared__ __align__(16) short ldsB[8192];
  int tid = threadIdx.x;
  int lane = tid & 63, wid = tid >> 6;
  int wm = wid >> 1, wn = wid & 1;
  int lane16 = lane & 15, qf = lane >> 4;
  int swzl = (lane16 >> 1) & 3;
  int qx = (qf ^ swzl) * 8;

  f32x4 acc[4][4];
#pragma unroll
  for (int r = 0; r < 4; ++r)
#pragma unroll
    for (int c = 0; c < 4; ++c) acc[r][c] = (f32x4)0.f;

  const __hip_bfloat16* w2e = w2t + (size_t)e * kF * kH;
  const __hip_bfloat16* htile = hbuf + (size_t)local * kHbufTile;
  const __hip_bfloat16* gB[4];
  short* lA[4];
  short* lB[4];
  int aoff[4];
#pragma unroll
  for (int it = 0; it < 4; ++it) {
    int s = it * 256 + tid;
    int m = (s >> 2) & 127, kk = s >> 9;
    int q = (s & 3) ^ ((s >> 3) & 3);
    aoff[it] = s * 8;
    gB[it] = w2e + (size_t)(nbase + m) * kF + kk * 32 + q * 8;
    lA[it] = &ldsA[s * 8];
    lB[it] = &ldsB[s * 8];
  }

  for (int k0 = 0; k0 < kF; k0 += 64) {
#pragma unroll
    for (int it = 0; it < 4; ++it) gld_lds16(htile + k0 * 128 + aoff[it], lA[it]);
#pragma unroll
    for (int it = 0; it < 4; ++it) gld_lds16(gB[it] + k0, lB[it]);
    __syncthreads();
#pragma unroll
    for (int kk = 0; kk < 2; ++kk) {
      short8 af[4], bfr[4];
#pragma unroll
      for (int r = 0; r < 4; ++r) {
        int mr = wm * 64 + r * 16 + lane16;
        af[r] = *(const short8*)&ldsA[(kk * 512 + mr * 4) * 8 + qx];
      }
#pragma unroll
      for (int c = 0; c < 4; ++c) {
        int mb = wn * 64 + c * 16 + lane16;
        bfr[c] = *(const short8*)&ldsB[(kk * 512 + mb * 4) * 8 + qx];
      }
#pragma unroll
      for (int r = 0; r < 4; ++r)
#pragma unroll
        for (int c = 0; c < 4; ++c)
          acc[r][c] = __builtin_amdgcn_mfma_f32_16x16x32_bf16(af[r], bfr[c], acc[r][c], 0, 0, 0);
    }
    __syncthreads();
  }

  int q4 = qf * 4;
#pragma unroll
  for (int c = 0; c < 4; ++c) {
    int ncol = wn * 64 + c * 16 + lane16;
    float bias = bf2f(b2[e * kH + nbase + ncol]);
#pragma unroll
    for (int r = 0; r < 4; ++r) {
      int s = (wm * 64 + r * 16) >> 5;
      int bb = tbraw[s];
      if (bb < 0) continue;
      float scale = sc[s];
#pragma unroll
      for (int g = 0; g < 4; ++g) {
        int m = wm * 64 + r * 16 + q4 + g;
        float v = (acc[r][c][g] + bias) * scale;
        out[((size_t)(bb * kT + (m & 31))) * kH + nbase + ncol] = v;
      }
    }
  }
}

}  // namespace

extern "C" void kernel_launch(void* const* d_in, const int* in_sizes, int n_in,
                              void* d_out, int out_size, void* d_ws, size_t ws_size,
                              hipStream_t stream) {
  (void)in_sizes; (void)n_in; (void)out_size;
  float* out = (float*)d_out;

  char* ws = (char*)d_ws;
  size_t off = 0;
  auto alloc = [&](size_t bytes) -> char* {
    char* p = ws + off;
    off = (off + bytes + 255) & ~(size_t)255;
    return p;
  };
  int*   flagX      = (int*)alloc(4);
  int*   flagG      = (int*)alloc(4);
  int*   flagW1     = (int*)alloc(4);
  int*   flagW2     = (int*)alloc(4);
  int*   cnt        = (int*)alloc(kE * 4);
  float* wsel       = (float*)alloc(kB * 4);
  int*   lists      = (int*)alloc((size_t)kE * kB * 4);
  int*   tileExpert = (int*)alloc(kMaxTiles * 4);
  int*   tileBatch  = (int*)alloc(kMaxTiles * 4 * 4);
  int*   numTiles   = (int*)alloc(4);
  __hip_bfloat16* w1t   = (__hip_bfloat16*)alloc((size_t)kE * kH * kF * 2);      // 14.2 MB
  __hip_bfloat16* w2t   = (__hip_bfloat16*)alloc((size_t)kE * kH * kF * 2);      // 14.2 MB
  __hip_bfloat16* xperm = (__hip_bfloat16*)alloc((size_t)kMaxTiles * kXPermTile * 2);  // 25.8 MB

  // adaptive hbuf chunk (deterministic in ws_size)
  size_t tileBytes = (size_t)kHbufTile * 2;  // 786432
  size_t avail = (ws_size > off + tileBytes) ? (ws_size - off) : tileBytes;
  int chunk = (int)(avail / tileBytes);
  if (chunk > kMaxChunk) chunk = kMaxChunk;
  if (chunk < 1) chunk = 1;
  __hip_bfloat16* hbuf = (__hip_bfloat16*)alloc((size_t)chunk * tileBytes);

  hipMemsetAsync(cnt, 0, kE * 4, stream);
  k_sniff<<<1, 256, 0, stream>>>((const unsigned short*)d_in[0], 4096, flagX);
  k_sniff<<<1, 256, 0, stream>>>((const unsigned short*)d_in[1], kE * kH, flagG);
  k_sniff<<<1, 256, 0, stream>>>((const unsigned short*)d_in[2], 4096, flagW1);
  k_sniff<<<1, 256, 0, stream>>>((const unsigned short*)d_in[4], 4096, flagW2);
  k_route<<<kB, 256, 0, stream>>>(d_in[0], d_in[1], flagX, flagG, wsel, cnt, lists);
  k_tiles<<<1, 64, 0, stream>>>(cnt, lists, tileExpert, tileBatch, numTiles);
  k_transpose<<<dim3(kF / 64, kH / 64, kE), 256, 0, stream>>>(d_in[2], w1t, kH, kF, flagW1);
  k_transpose<<<dim3(kH / 64, kF / 64, kE), 256, 0, stream>>>(d_in[4], w2t, kF, kH, flagW2);
  k_convert_x<<<dim3(kH / 64, kMaxTiles), 256, 0, stream>>>(d_in[0], flagX, tileBatch,
                                                            numTiles, xperm);
  for (int toff = 0; toff < kMaxTiles; toff += chunk) {
    k_ffn1<<<dim3(kF / 128, chunk), 256, 0, stream>>>(xperm, w1t,
                                                      (const __hip_bfloat16*)d_in[3],
                                                      tileExpert, numTiles, toff, hbuf);
    k_ffn2<<<dim3(kH / 128, chunk), 256, 0, stream>>>(hbuf, w2t,
                                                      (const __hip_bfloat16*)d_in[5], wsel,
                                                      tileExpert, tileBatch, numTiles,
                                                      toff, out);
  }
}

// Round 6
// 423.914 us; speedup vs baseline: 1.2063x; 1.0822x over previous
//
#include <hip/hip_runtime.h>
#include <hip/hip_bf16.h>
#include <cstdint>
#include <cstddef>

namespace {

constexpr int kB = 512, kT = 32, kH = 768, kF = 3072, kE = 3;
constexpr int kMaxTiles = 131;   // sum ceil(cnt_e/4) <= 131
constexpr int kMaxChunk = 131;
constexpr int kXPermTile = 128 * kH;   // 98304 elts per tile
constexpr int kHbufTile  = 128 * kF;   // 393216 elts per tile

typedef __attribute__((ext_vector_type(8))) short short8;
typedef __attribute__((ext_vector_type(4))) float f32x4;

__device__ __forceinline__ void gld_lds16(const void* g, void* l) {
  __builtin_amdgcn_global_load_lds(
      (const __attribute__((address_space(1))) void*)g,
      (__attribute__((address_space(3))) void*)l, 16, 0, 0);
}

__device__ __forceinline__ float bf2f(__hip_bfloat16 v) { return __bfloat162float(v); }
__device__ __forceinline__ unsigned short f2bfb(float f) {
  __hip_bfloat16 h = __float2bfloat16(f);
  return *reinterpret_cast<unsigned short*>(&h);
}

// ---- per-tensor dtype sniff (f32 seen as 16-bit words: ~25% have exp-field >= 0xC0)
__global__ void k_sniff(const unsigned short* __restrict__ w, int nwords,
                        int* __restrict__ flag) {
  __shared__ int cnt_s;
  if (threadIdx.x == 0) cnt_s = 0;
  __syncthreads();
  int local = 0;
  for (int i = threadIdx.x; i < nwords; i += 256) {
    unsigned e = (w[i] >> 7) & 0xFF;
    if (e >= 0xC0) ++local;
  }
  atomicAdd(&cnt_s, local);
  __syncthreads();
  if (threadIdx.x == 0) *flag = (cnt_s > 64) ? 1 : 0;
}

// ---------------- routing ----------------
__global__ void k_route(const void* __restrict__ xv, const void* __restrict__ Wgv,
                        const int* __restrict__ flagX, const int* __restrict__ flagG,
                        float* __restrict__ wsel,
                        int* __restrict__ cnt, int* __restrict__ lists) {
  bool fx = (*flagX != 0), fg = (*flagG != 0);
  const float* xf = (const float*)xv;
  const __hip_bfloat16* xb = (const __hip_bfloat16*)xv;
  const float* wf = (const float*)Wgv;
  const __hip_bfloat16* wb = (const __hip_bfloat16*)Wgv;
  int b = blockIdx.x;
  int tid = threadIdx.x;
  float a0 = 0.f, a1 = 0.f, a2 = 0.f;
  for (int h = tid; h < kH; h += 256) {
    size_t base = (size_t)b * kT * kH + h;
    float s = 0.f;
#pragma unroll
    for (int t = 0; t < kT; ++t) {
      size_t i = base + (size_t)t * kH;
      s += fx ? xf[i] : bf2f(xb[i]);
    }
    s *= (1.f / kT);
    a0 += s * (fg ? wf[0 * kH + h] : bf2f(wb[0 * kH + h]));
    a1 += s * (fg ? wf[1 * kH + h] : bf2f(wb[1 * kH + h]));
    a2 += s * (fg ? wf[2 * kH + h] : bf2f(wb[2 * kH + h]));
  }
  __shared__ float red[3][256];
  red[0][tid] = a0; red[1][tid] = a1; red[2][tid] = a2;
  __syncthreads();
  for (int s2 = 128; s2 > 0; s2 >>= 1) {
    if (tid < s2) {
      red[0][tid] += red[0][tid + s2];
      red[1][tid] += red[1][tid + s2];
      red[2][tid] += red[2][tid + s2];
    }
    __syncthreads();
  }
  if (tid == 0) {
    float l0 = red[0][0], l1 = red[1][0], l2 = red[2][0];
    int am = 0; float mx = l0;
    if (l1 > mx) { mx = l1; am = 1; }
    if (l2 > mx) { mx = l2; am = 2; }
    float e0 = expf(l0 - mx), e1 = expf(l1 - mx), e2 = expf(l2 - mx);
    float inv = 1.f / (e0 + e1 + e2);
    float sc = (am == 0 ? e0 : (am == 1 ? e1 : e2)) * inv;
    wsel[b] = sc;
    int pos = atomicAdd(&cnt[am], 1);
    lists[am * kB + pos] = b;
  }
}

// ---------------- pack batches into 128-row M-tiles ----------------
__global__ void k_tiles(const int* __restrict__ cnt, const int* __restrict__ lists,
                        int* __restrict__ tileExpert, int* __restrict__ tileBatch,
                        int* __restrict__ numTiles) {
  if (threadIdx.x == 0 && blockIdx.x == 0) {
    int t = 0;
    for (int e = 0; e < kE; ++e) {
      int c = cnt[e];
      for (int i = 0; i < c; i += 4) {
        tileExpert[t] = e;
        for (int s = 0; s < 4; ++s)
          tileBatch[t * 4 + s] = (i + s < c) ? lists[e * kB + i + s] : -1;
        ++t;
      }
    }
    *numTiles = t;
    for (int tt = t; tt < kMaxTiles; ++tt) {
      tileExpert[tt] = 0;
      for (int s = 0; s < 4; ++s) tileBatch[tt * 4 + s] = -1;
    }
  }
}

// ---------------- transpose + convert (vectorized): src [E][K][N] -> bf16 [E][N][K] ----------------
__global__ __launch_bounds__(256)
void k_transpose(const void* __restrict__ srcv, __hip_bfloat16* __restrict__ dst_,
                 int K, int N, const int* __restrict__ flag) {
  bool f32 = (*flag != 0);
  const float* sf = (const float*)srcv;
  const unsigned short* sb = (const unsigned short*)srcv;
  unsigned short* dst = (unsigned short*)dst_;
  __shared__ __align__(16) unsigned short t[64][73];
  int e = blockIdx.z;
  int n0 = blockIdx.x * 64, k0 = blockIdx.y * 64;
  size_t eoff = (size_t)e * K * N;
  int tr = threadIdx.x >> 4;          // 0..15
  int tc4 = (threadIdx.x & 15) * 4;   // 0..60
#pragma unroll
  for (int i = 0; i < 4; ++i) {
    int r = tr + 16 * i;
    size_t idx = eoff + (size_t)(k0 + r) * N + n0 + tc4;
    if (f32) {
      float4 u = *(const float4*)(sf + idx);
      t[r][tc4] = f2bfb(u.x); t[r][tc4 + 1] = f2bfb(u.y);
      t[r][tc4 + 2] = f2bfb(u.z); t[r][tc4 + 3] = f2bfb(u.w);
    } else {
      ushort4 u = *(const ushort4*)(sb + idx);
      t[r][tc4] = u.x; t[r][tc4 + 1] = u.y; t[r][tc4 + 2] = u.z; t[r][tc4 + 3] = u.w;
    }
  }
  __syncthreads();
#pragma unroll
  for (int i = 0; i < 4; ++i) {
    int rn = tr + 16 * i;  // n offset
    ushort4 v;
    v.x = t[tc4][rn]; v.y = t[tc4 + 1][rn]; v.z = t[tc4 + 2][rn]; v.w = t[tc4 + 3][rn];
    *(ushort4*)(dst + eoff + (size_t)(n0 + rn) * K + k0 + tc4) = v;
  }
}

// ---------------- convert + permute x into ffn1 A-staging order ----------------
// xperm[tile][kblk(12)][slot(1024)*8], slot = kk*512 + m*4 + (q ^ ((m>>1)&3))
__global__ __launch_bounds__(256)
void k_convert_x(const void* __restrict__ xv, const int* __restrict__ flagX,
                 const int* __restrict__ tileBatch, const int* __restrict__ numTiles,
                 __hip_bfloat16* __restrict__ xperm) {
  int tile = blockIdx.y;
  if (tile >= *numTiles) return;
  int kblk = blockIdx.x;
  bool fx = (*flagX != 0);
  const float* xf = (const float*)xv;
  const __hip_bfloat16* xb = (const __hip_bfloat16*)xv;
  int tb0 = tileBatch[tile * 4];
  int tb[4];
#pragma unroll
  for (int s = 0; s < 4; ++s) {
    int bb = tileBatch[tile * 4 + s];
    tb[s] = (bb < 0) ? tb0 : bb;
  }
  int tid = threadIdx.x;
  short8* dst = (short8*)(xperm + (size_t)tile * kXPermTile + kblk * 8192);
#pragma unroll
  for (int i = 0; i < 4; ++i) {
    int s = i * 256 + tid;
    int m = (s >> 2) & 127, kk = s >> 9;
    int q = (s & 3) ^ ((s >> 3) & 3);   // (m>>1)&3 == (s>>3)&3
    int row = tb[m >> 5] * kT + (m & 31);
    size_t src = (size_t)row * kH + kblk * 64 + kk * 32 + q * 8;
    short8 v;
    if (fx) {
      float4 u = *(const float4*)(xf + src);
      float4 w = *(const float4*)(xf + src + 4);
      v[0] = f2bfb(u.x); v[1] = f2bfb(u.y); v[2] = f2bfb(u.z); v[3] = f2bfb(u.w);
      v[4] = f2bfb(w.x); v[5] = f2bfb(w.y); v[6] = f2bfb(w.z); v[7] = f2bfb(w.w);
    } else {
      v = *(const short8*)(xb + src);
    }
    dst[s] = v;
  }
}

// ---------------- GEMM1: h = gelu(x @ W1[e] + b1), hbuf in ffn2-A-staging order ----------------
// grid (8, 3*chunk): xcd = blockIdx.x; j = blockIdx.y; tile = tileOff + j/3;
// nIdx = 8*(j%3) + xcd  -> each XCD reads only 3 weight strips (L2-resident)
__global__ __launch_bounds__(256, 2)
void k_ffn1(const __hip_bfloat16* __restrict__ xperm,
            const __hip_bfloat16* __restrict__ w1t,  // [E][F][H] bf16
            const __hip_bfloat16* __restrict__ b1,
            const int* __restrict__ tileExpert,
            const int* __restrict__ numTiles,
            int tileOff,
            __hip_bfloat16* __restrict__ hbuf) {
  int j = blockIdx.y;
  int local = j / 3;
  int tile = local + tileOff;
  if (tile >= *numTiles) return;
  int nIdx = 8 * (j % 3) + blockIdx.x;
  int nbase = nIdx * 128;
  int e = tileExpert[tile];
  __shared__ __align__(16) short ldsA[8192];
  __shared__ __align__(16) short ldsB[8192];
  int tid = threadIdx.x;
  int lane = tid & 63, wid = tid >> 6;
  int wm = wid >> 1, wn = wid & 1;
  int lane16 = lane & 15, qf = lane >> 4;
  int swzl = (lane16 >> 1) & 3;
  int qx = (qf ^ swzl) * 8;

  f32x4 acc[4][4];
#pragma unroll
  for (int r = 0; r < 4; ++r)
#pragma unroll
    for (int c = 0; c < 4; ++c) acc[r][c] = (f32x4)0.f;

  const __hip_bfloat16* w1e = w1t + (size_t)e * kF * kH;
  const __hip_bfloat16* xtile = xperm + (size_t)tile * kXPermTile;
  const __hip_bfloat16* gB[4];
  short* lA[4];
  short* lB[4];
  int aoff[4];
#pragma unroll
  for (int it = 0; it < 4; ++it) {
    int s = it * 256 + tid;
    int m = (s >> 2) & 127, kk = s >> 9;
    int q = (s & 3) ^ ((s >> 3) & 3);
    aoff[it] = s * 8;
    gB[it] = w1e + (size_t)(nbase + m) * kH + kk * 32 + q * 8;
    lA[it] = &ldsA[s * 8];
    lB[it] = &ldsB[s * 8];
  }

  for (int k0 = 0; k0 < kH; k0 += 64) {
#pragma unroll
    for (int it = 0; it < 4; ++it) gld_lds16(xtile + k0 * 128 + aoff[it], lA[it]);
#pragma unroll
    for (int it = 0; it < 4; ++it) gld_lds16(gB[it] + k0, lB[it]);
    __syncthreads();
#pragma unroll
    for (int kk = 0; kk < 2; ++kk) {
      short8 af[4], bfr[4];
#pragma unroll
      for (int r = 0; r < 4; ++r) {
        int mr = wm * 64 + r * 16 + lane16;
        af[r] = *(const short8*)&ldsA[(kk * 512 + mr * 4) * 8 + qx];
      }
#pragma unroll
      for (int c = 0; c < 4; ++c) {
        int mb = wn * 64 + c * 16 + lane16;
        bfr[c] = *(const short8*)&ldsB[(kk * 512 + mb * 4) * 8 + qx];
      }
#pragma unroll
      for (int r = 0; r < 4; ++r)
#pragma unroll
        for (int c = 0; c < 4; ++c)
          acc[r][c] = __builtin_amdgcn_mfma_f32_16x16x32_bf16(af[r], bfr[c], acc[r][c], 0, 0, 0);
    }
    __syncthreads();
  }

  // epilogue: write gelu(acc+bias) into hbuf in ffn2 A-staging order
  __hip_bfloat16* htile = hbuf + (size_t)local * kHbufTile;
  int q4 = qf * 4;
#pragma unroll
  for (int c = 0; c < 4; ++c) {
    int n = nbase + wn * 64 + c * 16 + lane16;
    int kblk2 = n >> 6, kkn = (n >> 5) & 1, qn = (n >> 3) & 3, jj = n & 7;
    float bias = bf2f(b1[e * kF + n]);
    __hip_bfloat16* hb = htile + kblk2 * 8192 + kkn * 4096 + jj;
#pragma unroll
    for (int r = 0; r < 4; ++r) {
#pragma unroll
      for (int g = 0; g < 4; ++g) {
        int m = wm * 64 + r * 16 + q4 + g;
        float v = acc[r][c][g] + bias;
        float ge = 0.5f * v * (1.f + erff(v * 0.70710678118654752f));
        hb[(m * 4 + (qn ^ ((m >> 1) & 3))) * 8] = __float2bfloat16(ge);
      }
    }
  }
}

// ---------------- GEMM2: out = (h @ W2[e] + b2) * score, f32 scatter ----------------
// grid (8, 6*ceil(chunk/8)): tile = tileOff + xcd + 8*(j/6); nbase = (j%6)*128
// -> all 6 N-blocks of a tile run on ONE XCD (A-strip L2-resident)
__global__ __launch_bounds__(256, 2)
void k_ffn2(const __hip_bfloat16* __restrict__ hbuf,
            const __hip_bfloat16* __restrict__ w2t,  // [E][H][F] bf16
            const __hip_bfloat16* __restrict__ b2,
            const float* __restrict__ wsel,
            const int* __restrict__ tileExpert,
            const int* __restrict__ tileBatch,
            const int* __restrict__ numTiles,
            int tileOff, int chunk,
            float* __restrict__ out) {
  int j = blockIdx.y;
  int local = blockIdx.x + 8 * (j / 6);
  if (local >= chunk) return;
  int tile = local + tileOff;
  if (tile >= *numTiles) return;
  int nbase = (j % 6) * 128;
  int e = tileExpert[tile];
  int tbraw[4];
  float sc[4];
#pragma unroll
  for (int s = 0; s < 4; ++s) {
    int bb = tileBatch[tile * 4 + s];
    tbraw[s] = bb;
    sc[s] = (bb >= 0) ? wsel[bb] : 0.f;
  }
  __shared__ __align__(16) short ldsA[8192];
  __shared__ __align__(16) short ldsB[8192];
  int tid = threadIdx.x;
  int lane = tid & 63, wid = tid >> 6;
  int wm = wid >> 1, wn = wid & 1;
  int lane16 = lane & 15, qf = lane >> 4;
  int swzl = (lane16 >> 1) & 3;
  int qx = (qf ^ swzl) * 8;

  f32x4 acc[4][4];
#pragma unroll
  for (int r = 0; r < 4; ++r)
#pragma unroll
    for (int c = 0; c < 4; ++c) acc[r][c] = (f32x4)0.f;

  const __hip_bfloat16* w2e = w2t + (size_t)e * kF * kH;
  const __hip_bfloat16* htile = hbuf + (size_t)local * kHbufTile;
  const __hip_bfloat16* gB[4];
  short* lA[4];
  short* lB[4];
  int aoff[4];
#pragma unroll
  for (int it = 0; it < 4; ++it) {
    int s = it * 256 + tid;
    int m = (s >> 2) & 127, kk = s >> 9;
    int q = (s & 3) ^ ((s >> 3) & 3);
    aoff[it] = s * 8;
    gB[it] = w2e + (size_t)(nbase + m) * kF + kk * 32 + q * 8;
    lA[it] = &ldsA[s * 8];
    lB[it] = &ldsB[s * 8];
  }

  for (int k0 = 0; k0 < kF; k0 += 64) {
#pragma unroll
    for (int it = 0; it < 4; ++it) gld_lds16(htile + k0 * 128 + aoff[it], lA[it]);
#pragma unroll
    for (int it = 0; it < 4; ++it) gld_lds16(gB[it] + k0, lB[it]);
    __syncthreads();
#pragma unroll
    for (int kk = 0; kk < 2; ++kk) {
      short8 af[4], bfr[4];
#pragma unroll
      for (int r = 0; r < 4; ++r) {
        int mr = wm * 64 + r * 16 + lane16;
        af[r] = *(const short8*)&ldsA[(kk * 512 + mr * 4) * 8 + qx];
      }
#pragma unroll
      for (int c = 0; c < 4; ++c) {
        int mb = wn * 64 + c * 16 + lane16;
        bfr[c] = *(const short8*)&ldsB[(kk * 512 + mb * 4) * 8 + qx];
      }
#pragma unroll
      for (int r = 0; r < 4; ++r)
#pragma unroll
        for (int c = 0; c < 4; ++c)
          acc[r][c] = __builtin_amdgcn_mfma_f32_16x16x32_bf16(af[r], bfr[c], acc[r][c], 0, 0, 0);
    }
    __syncthreads();
  }

  int q4 = qf * 4;
#pragma unroll
  for (int c = 0; c < 4; ++c) {
    int ncol = wn * 64 + c * 16 + lane16;
    float bias = bf2f(b2[e * kH + nbase + ncol]);
#pragma unroll
    for (int r = 0; r < 4; ++r) {
      int s = (wm * 64 + r * 16) >> 5;
      int bb = tbraw[s];
      if (bb < 0) continue;
      float scale = sc[s];
#pragma unroll
      for (int g = 0; g < 4; ++g) {
        int m = wm * 64 + r * 16 + q4 + g;
        float v = (acc[r][c][g] + bias) * scale;
        out[((size_t)(bb * kT + (m & 31))) * kH + nbase + ncol] = v;
      }
    }
  }
}

}  // namespace

extern "C" void kernel_launch(void* const* d_in, const int* in_sizes, int n_in,
                              void* d_out, int out_size, void* d_ws, size_t ws_size,
                              hipStream_t stream) {
  (void)in_sizes; (void)n_in; (void)out_size;
  float* out = (float*)d_out;

  char* ws = (char*)d_ws;
  size_t off = 0;
  auto alloc = [&](size_t bytes) -> char* {
    char* p = ws + off;
    off = (off + bytes + 255) & ~(size_t)255;
    return p;
  };
  int*   flagX      = (int*)alloc(4);
  int*   flagG      = (int*)alloc(4);
  int*   flagW1     = (int*)alloc(4);
  int*   flagW2     = (int*)alloc(4);
  int*   cnt        = (int*)alloc(kE * 4);
  float* wsel       = (float*)alloc(kB * 4);
  int*   lists      = (int*)alloc((size_t)kE * kB * 4);
  int*   tileExpert = (int*)alloc(kMaxTiles * 4);
  int*   tileBatch  = (int*)alloc(kMaxTiles * 4 * 4);
  int*   numTiles   = (int*)alloc(4);
  __hip_bfloat16* w1t   = (__hip_bfloat16*)alloc((size_t)kE * kH * kF * 2);      // 14.2 MB
  __hip_bfloat16* w2t   = (__hip_bfloat16*)alloc((size_t)kE * kH * kF * 2);      // 14.2 MB
  __hip_bfloat16* xperm = (__hip_bfloat16*)alloc((size_t)kMaxTiles * kXPermTile * 2);  // 25.8 MB

  // adaptive hbuf chunk (deterministic in ws_size)
  size_t tileBytes = (size_t)kHbufTile * 2;  // 786432
  size_t avail = (ws_size > off + tileBytes) ? (ws_size - off) : tileBytes;
  int chunk = (int)(avail / tileBytes);
  if (chunk > kMaxChunk) chunk = kMaxChunk;
  if (chunk < 1) chunk = 1;
  __hip_bfloat16* hbuf = (__hip_bfloat16*)alloc((size_t)chunk * tileBytes);

  hipMemsetAsync(cnt, 0, kE * 4, stream);
  k_sniff<<<1, 256, 0, stream>>>((const unsigned short*)d_in[0], 4096, flagX);
  k_sniff<<<1, 256, 0, stream>>>((const unsigned short*)d_in[1], kE * kH, flagG);
  k_sniff<<<1, 256, 0, stream>>>((const unsigned short*)d_in[2], 4096, flagW1);
  k_sniff<<<1, 256, 0, stream>>>((const unsigned short*)d_in[4], 4096, flagW2);
  k_route<<<kB, 256, 0, stream>>>(d_in[0], d_in[1], flagX, flagG, wsel, cnt, lists);
  k_tiles<<<1, 64, 0, stream>>>(cnt, lists, tileExpert, tileBatch, numTiles);
  k_transpose<<<dim3(kF / 64, kH / 64, kE), 256, 0, stream>>>(d_in[2], w1t, kH, kF, flagW1);
  k_transpose<<<dim3(kH / 64, kF / 64, kE), 256, 0, stream>>>(d_in[4], w2t, kF, kH, flagW2);
  k_convert_x<<<dim3(kH / 64, kMaxTiles), 256, 0, stream>>>(d_in[0], flagX, tileBatch,
                                                            numTiles, xperm);
  for (int toff = 0; toff < kMaxTiles; toff += chunk) {
    k_ffn1<<<dim3(8, 3 * chunk), 256, 0, stream>>>(xperm, w1t,
                                                   (const __hip_bfloat16*)d_in[3],
                                                   tileExpert, numTiles, toff, hbuf);
    int rows2 = (chunk + 7) / 8;
    k_ffn2<<<dim3(8, 6 * rows2), 256, 0, stream>>>(hbuf, w2t,
                                                   (const __hip_bfloat16*)d_in[5], wsel,
                                                   tileExpert, tileBatch, numTiles,
                                                   toff, chunk, out);
  }
}